// Round 8
// baseline (131.131 us; speedup 1.0000x reference)
//
#include <hip/hip_runtime.h>
#include <hip/hip_fp16.h>

#define NS 512
#define NR 32768
#define NB 1024
#define Q 16                 // r-splits (sixteenths)
#define NQ (NR / Q)          // 2048 reactions per split
#define G 8                  // batches per block
#define NG (NB / G)          // 128 batch groups
#define ELLK 64              // slots per (split, species); mean 12

typedef unsigned short u16x4 __attribute__((ext_vector_type(4)));

// ws layout (bytes):
//   pA   float4[NR]          @ 0       (524288)  alpha,beta,gamma,cr_coef
//   pB   float2[NR]          @ 524288  (262144)  fuv_coef, (s1|s2<<16) bits
//   cnt  int[Q*NS]           @ 786432  (32768)
//   ell  u16[Q][NS][ELLK]    @ 819200  (1048576) row-major per species
// total 1,867,776 B

static __device__ __forceinline__ float rfl(float v) {
  return __int_as_float(__builtin_amdgcn_readfirstlane(__float_as_int(v)));
}
static __device__ __forceinline__ unsigned int pkrtz(float a, float b) {
  auto h = __builtin_amdgcn_cvt_pkrtz(a, b);
  return *reinterpret_cast<unsigned int*>(&h);
}
static __device__ __forceinline__ __half2 bch2(unsigned int w) {
  return *reinterpret_cast<__half2*>(&w);
}
static __device__ __forceinline__ unsigned int h2u(__half2 h) {
  return *reinterpret_cast<unsigned int*>(&h);
}

// Merged prep + find_pr + out-zeroing. Grid 1024 = 32 r-blocks x 32 s-blocks.
__global__ __launch_bounds__(256) void build(
    const float* __restrict__ inc, const int* __restrict__ msi,
    const float* __restrict__ alpha, const float* __restrict__ beta,
    const float* __restrict__ gam,   const float* __restrict__ crc,
    const float* __restrict__ fvc,
    float4* __restrict__ pA, float2* __restrict__ pB,
    int* __restrict__ cnt, unsigned short* __restrict__ ell,
    float* __restrict__ out) {
  int rblk = blockIdx.x & 31;
  int sblk = blockIdx.x >> 5;
  int t = threadIdx.x;
  int rbase = rblk * 1024 + 4 * t;

  // ---- pr scan over 16 s-rows ----
  int4 a = reinterpret_cast<const int4*>(msi)[rbase >> 1];
  int4 b = reinterpret_cast<const int4*>(msi)[(rbase >> 1) + 1];
  int s1v[4] = {a.x, a.z, b.x, b.z};
  int s2v[4] = {a.y, a.w, b.y, b.w};
  int pr[4] = {-1, -1, -1, -1};
  int s0 = sblk * 16;
#pragma unroll
  for (int ss = 0; ss < 16; ++ss) {
    int s = s0 + ss;
    float4 v = reinterpret_cast<const float4*>(inc)[((size_t)s * NR + rbase) >> 2];
    float vv[4] = {v.x, v.y, v.z, v.w};
#pragma unroll
    for (int j = 0; j < 4; ++j) {
      float c = vv[j] + (float)(s == s1v[j]) + (float)(s == s2v[j]);
      if (c > 0.5f) pr[j] = s;
    }
  }
#pragma unroll
  for (int j = 0; j < 4; ++j) {
    if (pr[j] >= 0) {
      int r = rbase + j;
      int e16 = r >> 11;
      int p = atomicAdd(&cnt[e16 * NS + pr[j]], 1);
      if (p < ELLK)
        ell[((e16 * NS + pr[j]) << 6) + p] = (unsigned short)(r & (NQ - 1));
    }
  }

  // ---- pack duties: 32 reactions per block ----
  if (t < 32) {
    int r = rblk * 1024 + sblk * 32 + t;
    pA[r] = make_float4(alpha[r], beta[r], gam[r], crc[r]);
    int s1 = msi[2 * r], s2 = msi[2 * r + 1];
    pB[r] = make_float2(fvc[r], __int_as_float(s1 | (s2 << 16)));
    int e16 = r >> 11;
    unsigned short neg = (unsigned short)((r & (NQ - 1)) | 0x8000);
    int p1 = atomicAdd(&cnt[e16 * NS + s1], 1);
    if (p1 < ELLK) ell[((e16 * NS + s1) << 6) + p1] = neg;
    int p2 = atomicAdd(&cnt[e16 * NS + s2], 1);
    if (p2 < ELLK) ell[((e16 * NS + s2) << 6) + p2] = neg;
  }

  // ---- zero d_out slice: 128 float4 per block x 1024 blocks = 2 MB ----
  if (t < 128) {
    reinterpret_cast<float4*>(out)[blockIdx.x * 128 + t] =
        make_float4(0.f, 0.f, 0.f, 0.f);
  }
}

// One block per (batch-group, sixteenth). 512 threads, 43 KB LDS -> 3 blocks/CU.
__global__ __launch_bounds__(512, 6) void fused(
    const float* __restrict__ ab, const float* __restrict__ temp,
    const float* __restrict__ crr, const float* __restrict__ fvr,
    const float4* __restrict__ pA, const float2* __restrict__ pB,
    const int* __restrict__ cnt, const unsigned short* __restrict__ ell,
    float* __restrict__ out) {
  __shared__ uint4 gL[NQ];            // 32 KB: 4x half2 = 8 batches per reaction
  __shared__ uint4 abH[NS];           // 8 KB: 4x half2 ab per species (8 batches)
  __shared__ unsigned short cS[NS];   // 1 KB
  __shared__ unsigned int permL[NS];  // 2 KB
  int t = threadIdx.x;
  int grp = blockIdx.x & (NG - 1);
  int e16 = blockIdx.x >> 7;
  int rbase = e16 * NQ;

  float av[G];
#pragma unroll
  for (int i = 0; i < G; ++i) av[i] = ab[(size_t)(grp + i * NG) * NS + t];
  abH[t] = make_uint4(h2u(__floats2half2_rn(av[0], av[1])),
                      h2u(__floats2half2_rn(av[2], av[3])),
                      h2u(__floats2half2_rn(av[4], av[5])),
                      h2u(__floats2half2_rn(av[6], av[7])));
  int myc = cnt[e16 * NS + t];
  myc = myc < ELLK ? myc : ELLK;
  cS[t] = (unsigned short)myc;

  float lt[G], mg[G], cb[G], fb[G];
#pragma unroll
  for (int i = 0; i < G; ++i) {
    int b = grp + i * NG;
    float T = rfl(temp[b]);
    lt[i] = rfl(log2f(T * (1.0f / 300.0f)));
    mg[i] = rfl(-1.4426950408889634f / T);
    cb[i] = rfl(crr[b]);
    fb[i] = rfl(fvr[b]);
  }
  __syncthreads();

  // ---- rank sort (VALU-only, overlaps phase-1 LDS stalls) ----
  int rank = 0;
#pragma unroll 8
  for (int s = 0; s < NS; ++s) {
    int c = cS[s];
    rank += (c > myc) || (c == myc && s < t);
  }
  permL[rank] = (unsigned int)t | ((unsigned int)myc << 16);

  // ---- phase 1: rates * factors for 8 batches ----
#pragma unroll
  for (int it = 0; it < NQ / 512; ++it) {
    int rl = t + 512 * it;
    float4 a4 = pA[rbase + rl];
    float2 bb = pB[rbase + rl];
    int idx = __float_as_int(bb.y);
    uint4 u = abH[idx & 0xffff];
    uint4 v = abH[idx >> 16];
    float2 F01 = __half22float2(__hmul2(bch2(u.x), bch2(v.x)));
    float2 F23 = __half22float2(__hmul2(bch2(u.y), bch2(v.y)));
    float2 F45 = __half22float2(__hmul2(bch2(u.z), bch2(v.z)));
    float2 F67 = __half22float2(__hmul2(bch2(u.w), bch2(v.w)));
#define RATE(i) fmaf(a4.x, exp2f(fmaf(a4.y, lt[i], a4.z * mg[i])), \
                     fmaf(a4.w, cb[i], bb.x * fb[i]))
    unsigned int w01 = pkrtz(RATE(0) * F01.x, RATE(1) * F01.y);
    unsigned int w23 = pkrtz(RATE(2) * F23.x, RATE(3) * F23.y);
    unsigned int w45 = pkrtz(RATE(4) * F45.x, RATE(5) * F45.y);
    unsigned int w67 = pkrtz(RATE(6) * F67.x, RATE(7) * F67.y);
#undef RATE
    gL[rl] = make_uint4(w01, w23, w45, w67);
  }
  __syncthreads();

  // ---- phase 2: gather owned (rank-balanced) species column ----
  unsigned int pc = permL[t];
  int sp = pc & 0xffff;
  int cs = pc >> 16;
  const unsigned short* row = ell + ((size_t)(e16 * NS + sp) << 6);
  __half2 A01 = __float2half2_rn(0.f), A23 = A01, A45 = A01, A67 = A01;
  for (int k = 0; k < cs; k += 4) {
    u16x4 ev = *reinterpret_cast<const u16x4*>(row + k);
    uint4 gg[4];
#pragma unroll
    for (int j = 0; j < 4; ++j) gg[j] = gL[ev[j] & (NQ - 1)];
#pragma unroll
    for (int j = 0; j < 4; ++j) {
      unsigned int m = (k + j) < cs ? 0xFFFFFFFFu : 0u;
      unsigned int se = ev[j] & 0x8000u;
      se |= se << 16;
      A01 = __hadd2(A01, bch2((gg[j].x ^ se) & m));
      A23 = __hadd2(A23, bch2((gg[j].y ^ se) & m));
      A45 = __hadd2(A45, bch2((gg[j].z ^ se) & m));
      A67 = __hadd2(A67, bch2((gg[j].w ^ se) & m));
    }
  }

  // ---- de-permute via 8 conflict-free float rows in dead gL, then atomics ----
  float2 o01 = __half22float2(A01);
  float2 o23 = __half22float2(A23);
  float2 o45 = __half22float2(A45);
  float2 o67 = __half22float2(A67);
  __syncthreads();
  float (*stg)[NS] = reinterpret_cast<float(*)[NS]>(gL);
  stg[0][sp] = o01.x; stg[1][sp] = o01.y;
  stg[2][sp] = o23.x; stg[3][sp] = o23.y;
  stg[4][sp] = o45.x; stg[5][sp] = o45.y;
  stg[6][sp] = o67.x; stg[7][sp] = o67.y;
  __syncthreads();
#pragma unroll
  for (int i = 0; i < G; ++i)
    unsafeAtomicAdd(&out[(size_t)(grp + i * NG) * NS + t], stg[i][t]);
}

extern "C" void kernel_launch(void* const* d_in, const int* in_sizes, int n_in,
                              void* d_out, int out_size, void* d_ws, size_t ws_size,
                              hipStream_t stream) {
  const float* ab    = (const float*)d_in[1];
  const float* temp  = (const float*)d_in[2];
  const float* crr   = (const float*)d_in[3];
  const float* fvr   = (const float*)d_in[4];
  const float* inc   = (const float*)d_in[5];
  const float* alpha = (const float*)d_in[6];
  const float* beta  = (const float*)d_in[7];
  const float* gam   = (const float*)d_in[8];
  const float* crc   = (const float*)d_in[9];
  const float* fvc   = (const float*)d_in[10];
  const int*   msi   = (const int*)d_in[12];

  char* ws = (char*)d_ws;
  float4* pA           = (float4*)(ws);
  float2* pB           = (float2*)(ws + 524288);
  int* cnt             = (int*)(ws + 786432);
  unsigned short* ellp = (unsigned short*)(ws + 819200);
  float* out = (float*)d_out;

  hipMemsetAsync(cnt, 0, Q * NS * sizeof(int), stream);
  build<<<1024, 256, 0, stream>>>(inc, msi, alpha, beta, gam, crc, fvc,
                                  pA, pB, cnt, ellp, out);
  fused<<<NG * Q, 512, 0, stream>>>(ab, temp, crr, fvr, pA, pB, cnt, ellp, out);
}

// Round 9
// 83.099 us; speedup vs baseline: 1.5780x; 1.5780x over previous
//
#include <hip/hip_runtime.h>
#include <hip/hip_fp16.h>

#define NS 512
#define NR 32768
#define NB 1024
#define Q 16                 // r-splits (sixteenths)
#define NQ (NR / Q)          // 2048 reactions per split
#define G 8                  // batches per block
#define NG (NB / G)          // 128 batch groups
#define ELLK 64              // slots per (split, species); mean 12

typedef unsigned short u16x4 __attribute__((ext_vector_type(4)));

// ws layout (bytes):
//   pA   float4[NR]          @ 0       (524288)  alpha,beta,gamma,cr_coef
//   pB   float2[NR]          @ 524288  (262144)  fuv_coef, (s1|s2<<16) bits
//   cnt  int[Q*NS]           @ 786432  (32768)
//   perm uint[Q*NS]          @ 819200  (32768)   rank -> (s | cnt<<16)
//   ell  u16[Q][NS][ELLK]    @ 851968  (1048576) row-major per species
// total 1,900,544 B

static __device__ __forceinline__ float rfl(float v) {
  return __int_as_float(__builtin_amdgcn_readfirstlane(__float_as_int(v)));
}
static __device__ __forceinline__ unsigned int pkrtz(float a, float b) {
  auto h = __builtin_amdgcn_cvt_pkrtz(a, b);
  return *reinterpret_cast<unsigned int*>(&h);
}
static __device__ __forceinline__ __half2 bch2(unsigned int w) {
  return *reinterpret_cast<__half2*>(&w);
}
static __device__ __forceinline__ unsigned int h2u(__half2 h) {
  return *reinterpret_cast<unsigned int*>(&h);
}

// Merged prep + find_pr + out-zeroing. Grid 1024 = 32 r-blocks x 32 s-blocks.
__global__ __launch_bounds__(256) void build(
    const float* __restrict__ inc, const int* __restrict__ msi,
    const float* __restrict__ alpha, const float* __restrict__ beta,
    const float* __restrict__ gam,   const float* __restrict__ crc,
    const float* __restrict__ fvc,
    float4* __restrict__ pA, float2* __restrict__ pB,
    int* __restrict__ cnt, unsigned short* __restrict__ ell,
    float* __restrict__ out) {
  int rblk = blockIdx.x & 31;
  int sblk = blockIdx.x >> 5;
  int t = threadIdx.x;
  int rbase = rblk * 1024 + 4 * t;

  // ---- pr scan over 16 s-rows ----
  int4 a = reinterpret_cast<const int4*>(msi)[rbase >> 1];
  int4 b = reinterpret_cast<const int4*>(msi)[(rbase >> 1) + 1];
  int s1v[4] = {a.x, a.z, b.x, b.z};
  int s2v[4] = {a.y, a.w, b.y, b.w};
  int pr[4] = {-1, -1, -1, -1};
  int s0 = sblk * 16;
#pragma unroll
  for (int ss = 0; ss < 16; ++ss) {
    int s = s0 + ss;
    float4 v = reinterpret_cast<const float4*>(inc)[((size_t)s * NR + rbase) >> 2];
    float vv[4] = {v.x, v.y, v.z, v.w};
#pragma unroll
    for (int j = 0; j < 4; ++j) {
      float c = vv[j] + (float)(s == s1v[j]) + (float)(s == s2v[j]);
      if (c > 0.5f) pr[j] = s;
    }
  }
#pragma unroll
  for (int j = 0; j < 4; ++j) {
    if (pr[j] >= 0) {
      int r = rbase + j;
      int e16 = r >> 11;
      int p = atomicAdd(&cnt[e16 * NS + pr[j]], 1);
      if (p < ELLK)
        ell[((e16 * NS + pr[j]) << 6) + p] = (unsigned short)(r & (NQ - 1));
    }
  }

  // ---- pack duties: 32 reactions per block ----
  if (t < 32) {
    int r = rblk * 1024 + sblk * 32 + t;
    pA[r] = make_float4(alpha[r], beta[r], gam[r], crc[r]);
    int s1 = msi[2 * r], s2 = msi[2 * r + 1];
    pB[r] = make_float2(fvc[r], __int_as_float(s1 | (s2 << 16)));
    int e16 = r >> 11;
    unsigned short neg = (unsigned short)((r & (NQ - 1)) | 0x8000);
    int p1 = atomicAdd(&cnt[e16 * NS + s1], 1);
    if (p1 < ELLK) ell[((e16 * NS + s1) << 6) + p1] = neg;
    int p2 = atomicAdd(&cnt[e16 * NS + s2], 1);
    if (p2 < ELLK) ell[((e16 * NS + s2) << 6) + p2] = neg;
  }

  // ---- zero d_out slice: 128 float4 per block x 1024 blocks = 2 MB ----
  if (t < 128) {
    reinterpret_cast<float4*>(out)[blockIdx.x * 128 + t] =
        make_float4(0.f, 0.f, 0.f, 0.f);
  }
}

// Per-split descending count-sort of species -> perm[rank] = s | cnt<<16.
// 16 blocks only — batch-independent, so compute once, not per fused block.
__global__ __launch_bounds__(512) void balance(
    const int* __restrict__ cnt, unsigned int* __restrict__ perm) {
  __shared__ unsigned short c[NS];
  int e16 = blockIdx.x;
  int t = threadIdx.x;
  int my = cnt[e16 * NS + t];
  my = my < ELLK ? my : ELLK;
  c[t] = (unsigned short)my;
  __syncthreads();
  int rank = 0;
#pragma unroll 8
  for (int s = 0; s < NS; ++s) {
    int cs = c[s];
    rank += (cs > my) || (cs == my && s < t);
  }
  perm[e16 * NS + rank] = (unsigned int)t | ((unsigned int)my << 16);
}

// One block per (batch-group, sixteenth). 512 threads, 40 KB LDS -> 4 blocks/CU.
__global__ __launch_bounds__(512, 8) void fused(
    const float* __restrict__ ab, const float* __restrict__ temp,
    const float* __restrict__ crr, const float* __restrict__ fvr,
    const float4* __restrict__ pA, const float2* __restrict__ pB,
    const unsigned int* __restrict__ perm, const unsigned short* __restrict__ ell,
    float* __restrict__ out) {
  __shared__ uint4 gL[NQ];            // 32 KB: 4x half2 = 8 batches per reaction
  __shared__ uint4 abH[NS];           // 8 KB: 4x half2 ab per species (8 batches)
  int t = threadIdx.x;
  int grp = blockIdx.x & (NG - 1);
  int e16 = blockIdx.x >> 7;
  int rbase = e16 * NQ;

  float av[G];
#pragma unroll
  for (int i = 0; i < G; ++i) av[i] = ab[(size_t)(grp + i * NG) * NS + t];
  abH[t] = make_uint4(h2u(__floats2half2_rn(av[0], av[1])),
                      h2u(__floats2half2_rn(av[2], av[3])),
                      h2u(__floats2half2_rn(av[4], av[5])),
                      h2u(__floats2half2_rn(av[6], av[7])));

  float lt[G], mg[G], cb[G], fb[G];
#pragma unroll
  for (int i = 0; i < G; ++i) {
    int b = grp + i * NG;
    float T = rfl(temp[b]);
    lt[i] = rfl(log2f(T * (1.0f / 300.0f)));
    mg[i] = rfl(-1.4426950408889634f / T);
    cb[i] = rfl(crr[b]);
    fb[i] = rfl(fvr[b]);
  }
  unsigned int pc = perm[e16 * NS + t];   // rank-balanced ownership
  __syncthreads();

  // ---- phase 1: rates * factors for 8 batches ----
#pragma unroll
  for (int it = 0; it < NQ / 512; ++it) {
    int rl = t + 512 * it;
    float4 a4 = pA[rbase + rl];
    float2 bb = pB[rbase + rl];
    int idx = __float_as_int(bb.y);
    uint4 u = abH[idx & 0xffff];
    uint4 v = abH[idx >> 16];
    float2 F01 = __half22float2(__hmul2(bch2(u.x), bch2(v.x)));
    float2 F23 = __half22float2(__hmul2(bch2(u.y), bch2(v.y)));
    float2 F45 = __half22float2(__hmul2(bch2(u.z), bch2(v.z)));
    float2 F67 = __half22float2(__hmul2(bch2(u.w), bch2(v.w)));
#define RATE(i) fmaf(a4.x, exp2f(fmaf(a4.y, lt[i], a4.z * mg[i])), \
                     fmaf(a4.w, cb[i], bb.x * fb[i]))
    unsigned int w01 = pkrtz(RATE(0) * F01.x, RATE(1) * F01.y);
    unsigned int w23 = pkrtz(RATE(2) * F23.x, RATE(3) * F23.y);
    unsigned int w45 = pkrtz(RATE(4) * F45.x, RATE(5) * F45.y);
    unsigned int w67 = pkrtz(RATE(6) * F67.x, RATE(7) * F67.y);
#undef RATE
    gL[rl] = make_uint4(w01, w23, w45, w67);
  }
  __syncthreads();

  // ---- phase 2: gather owned (rank-balanced) species column ----
  int sp = pc & 0xffff;
  int cs = pc >> 16;
  const unsigned short* row = ell + ((size_t)(e16 * NS + sp) << 6);
  __half2 A01 = __float2half2_rn(0.f), A23 = A01, A45 = A01, A67 = A01;
  for (int k = 0; k < cs; k += 4) {
    u16x4 ev = *reinterpret_cast<const u16x4*>(row + k);
    uint4 gg[4];
#pragma unroll
    for (int j = 0; j < 4; ++j) gg[j] = gL[ev[j] & (NQ - 1)];
#pragma unroll
    for (int j = 0; j < 4; ++j) {
      unsigned int m = (k + j) < cs ? 0xFFFFFFFFu : 0u;
      unsigned int se = ev[j] & 0x8000u;
      se |= se << 16;
      A01 = __hadd2(A01, bch2((gg[j].x ^ se) & m));
      A23 = __hadd2(A23, bch2((gg[j].y ^ se) & m));
      A45 = __hadd2(A45, bch2((gg[j].z ^ se) & m));
      A67 = __hadd2(A67, bch2((gg[j].w ^ se) & m));
    }
  }

  // ---- de-permute via 8 conflict-free float rows in dead gL, then atomics ----
  float2 o01 = __half22float2(A01);
  float2 o23 = __half22float2(A23);
  float2 o45 = __half22float2(A45);
  float2 o67 = __half22float2(A67);
  __syncthreads();
  float (*stg)[NS] = reinterpret_cast<float(*)[NS]>(gL);
  stg[0][sp] = o01.x; stg[1][sp] = o01.y;
  stg[2][sp] = o23.x; stg[3][sp] = o23.y;
  stg[4][sp] = o45.x; stg[5][sp] = o45.y;
  stg[6][sp] = o67.x; stg[7][sp] = o67.y;
  __syncthreads();
#pragma unroll
  for (int i = 0; i < G; ++i)
    unsafeAtomicAdd(&out[(size_t)(grp + i * NG) * NS + t], stg[i][t]);
}

extern "C" void kernel_launch(void* const* d_in, const int* in_sizes, int n_in,
                              void* d_out, int out_size, void* d_ws, size_t ws_size,
                              hipStream_t stream) {
  const float* ab    = (const float*)d_in[1];
  const float* temp  = (const float*)d_in[2];
  const float* crr   = (const float*)d_in[3];
  const float* fvr   = (const float*)d_in[4];
  const float* inc   = (const float*)d_in[5];
  const float* alpha = (const float*)d_in[6];
  const float* beta  = (const float*)d_in[7];
  const float* gam   = (const float*)d_in[8];
  const float* crc   = (const float*)d_in[9];
  const float* fvc   = (const float*)d_in[10];
  const int*   msi   = (const int*)d_in[12];

  char* ws = (char*)d_ws;
  float4* pA           = (float4*)(ws);
  float2* pB           = (float2*)(ws + 524288);
  int* cnt             = (int*)(ws + 786432);
  unsigned int* perm   = (unsigned int*)(ws + 819200);
  unsigned short* ellp = (unsigned short*)(ws + 851968);
  float* out = (float*)d_out;

  hipMemsetAsync(cnt, 0, Q * NS * sizeof(int), stream);
  build<<<1024, 256, 0, stream>>>(inc, msi, alpha, beta, gam, crc, fvc,
                                  pA, pB, cnt, ellp, out);
  balance<<<Q, 512, 0, stream>>>(cnt, perm);
  fused<<<NG * Q, 512, 0, stream>>>(ab, temp, crr, fvr, pA, pB, perm, ellp, out);
}

// Round 10
// 80.276 us; speedup vs baseline: 1.6335x; 1.0352x over previous
//
#include <hip/hip_runtime.h>
#include <hip/hip_fp16.h>

#define NS 512
#define NR 32768
#define NB 1024
#define Q 16                 // r-splits (sixteenths)
#define NQ (NR / Q)          // 2048 reactions per split
#define G 8                  // batches per block
#define NG (NB / G)          // 128 batch groups
#define ELLK 64              // slots per (split, species); mean 12, max ~26 observed-safe

typedef unsigned short u16x4 __attribute__((ext_vector_type(4)));

// ws layout (bytes):
//   pA   float4[NR]          @ 0       (524288)  alpha,beta,gamma,cr_coef
//   pB   float2[NR]          @ 524288  (262144)  fuv_coef, (s1|s2<<16) bits
//   cnt  int[Q*NS]           @ 786432  (32768)
//   perm uint[Q*NS]          @ 819200  (32768)   rank -> (s | cnt<<16)
//   ell  u16[Q][NS][ELLK]    @ 851968  (1048576) row-major per species
// total 1,900,544 B

static __device__ __forceinline__ float rfl(float v) {
  return __int_as_float(__builtin_amdgcn_readfirstlane(__float_as_int(v)));
}
static __device__ __forceinline__ unsigned int pkrtz(float a, float b) {
  auto h = __builtin_amdgcn_cvt_pkrtz(a, b);
  return *reinterpret_cast<unsigned int*>(&h);
}
static __device__ __forceinline__ __half2 bch2(unsigned int w) {
  return *reinterpret_cast<__half2*>(&w);
}
static __device__ __forceinline__ unsigned int h2u(__half2 h) {
  return *reinterpret_cast<unsigned int*>(&h);
}

// Merged prep + find_pr + out-zeroing. Grid 1024 = 32 r-blocks x 32 s-blocks.
__global__ __launch_bounds__(256) void build(
    const float* __restrict__ inc, const int* __restrict__ msi,
    const float* __restrict__ alpha, const float* __restrict__ beta,
    const float* __restrict__ gam,   const float* __restrict__ crc,
    const float* __restrict__ fvc,
    float4* __restrict__ pA, float2* __restrict__ pB,
    int* __restrict__ cnt, unsigned short* __restrict__ ell,
    float* __restrict__ out) {
  int rblk = blockIdx.x & 31;
  int sblk = blockIdx.x >> 5;
  int t = threadIdx.x;
  int rbase = rblk * 1024 + 4 * t;

  // ---- pr scan over 16 s-rows ----
  int4 a = reinterpret_cast<const int4*>(msi)[rbase >> 1];
  int4 b = reinterpret_cast<const int4*>(msi)[(rbase >> 1) + 1];
  int s1v[4] = {a.x, a.z, b.x, b.z};
  int s2v[4] = {a.y, a.w, b.y, b.w};
  int pr[4] = {-1, -1, -1, -1};
  int s0 = sblk * 16;
#pragma unroll
  for (int ss = 0; ss < 16; ++ss) {
    int s = s0 + ss;
    float4 v = reinterpret_cast<const float4*>(inc)[((size_t)s * NR + rbase) >> 2];
    float vv[4] = {v.x, v.y, v.z, v.w};
#pragma unroll
    for (int j = 0; j < 4; ++j) {
      float c = vv[j] + (float)(s == s1v[j]) + (float)(s == s2v[j]);
      if (c > 0.5f) pr[j] = s;
    }
  }
#pragma unroll
  for (int j = 0; j < 4; ++j) {
    if (pr[j] >= 0) {
      int r = rbase + j;
      int e16 = r >> 11;
      int p = atomicAdd(&cnt[e16 * NS + pr[j]], 1);
      if (p < ELLK)
        ell[((e16 * NS + pr[j]) << 6) + p] = (unsigned short)(r & (NQ - 1));
    }
  }

  // ---- pack duties: 32 reactions per block ----
  if (t < 32) {
    int r = rblk * 1024 + sblk * 32 + t;
    pA[r] = make_float4(alpha[r], beta[r], gam[r], crc[r]);
    int s1 = msi[2 * r], s2 = msi[2 * r + 1];
    pB[r] = make_float2(fvc[r], __int_as_float(s1 | (s2 << 16)));
    int e16 = r >> 11;
    unsigned short neg = (unsigned short)((r & (NQ - 1)) | 0x8000);
    int p1 = atomicAdd(&cnt[e16 * NS + s1], 1);
    if (p1 < ELLK) ell[((e16 * NS + s1) << 6) + p1] = neg;
    int p2 = atomicAdd(&cnt[e16 * NS + s2], 1);
    if (p2 < ELLK) ell[((e16 * NS + s2) << 6) + p2] = neg;
  }

  // ---- zero d_out slice: 128 float4 per block x 1024 blocks = 2 MB ----
  if (t < 128) {
    reinterpret_cast<float4*>(out)[blockIdx.x * 128 + t] =
        make_float4(0.f, 0.f, 0.f, 0.f);
  }
}

// Per-split descending count-sort of species -> perm[rank] = s | cnt<<16.
__global__ __launch_bounds__(512) void balance(
    const int* __restrict__ cnt, unsigned int* __restrict__ perm) {
  __shared__ unsigned short c[NS];
  int e16 = blockIdx.x;
  int t = threadIdx.x;
  int my = cnt[e16 * NS + t];
  my = my < ELLK ? my : ELLK;
  c[t] = (unsigned short)my;
  __syncthreads();
  int rank = 0;
#pragma unroll 8
  for (int s = 0; s < NS; ++s) {
    int cs = c[s];
    rank += (cs > my) || (cs == my && s < t);
  }
  perm[e16 * NS + rank] = (unsigned int)t | ((unsigned int)my << 16);
}

// One block per (batch-group, sixteenth). 512 threads, 40 KB LDS -> 4 blocks/CU.
__global__ __launch_bounds__(512, 8) void fused(
    const float* __restrict__ ab, const float* __restrict__ temp,
    const float* __restrict__ crr, const float* __restrict__ fvr,
    const float4* __restrict__ pA, const float2* __restrict__ pB,
    const unsigned int* __restrict__ perm, const unsigned short* __restrict__ ell,
    float* __restrict__ out) {
  __shared__ uint4 gL[NQ];            // 32 KB: 4x half2 = 8 batches per reaction
  __shared__ uint4 abH[NS];           // 8 KB: 4x half2 ab per species (8 batches)
  int t = threadIdx.x;
  int grp = blockIdx.x & (NG - 1);
  int e16 = blockIdx.x >> 7;
  int rbase = e16 * NQ;

  float av[G];
#pragma unroll
  for (int i = 0; i < G; ++i) av[i] = ab[(size_t)(grp + i * NG) * NS + t];
  abH[t] = make_uint4(h2u(__floats2half2_rn(av[0], av[1])),
                      h2u(__floats2half2_rn(av[2], av[3])),
                      h2u(__floats2half2_rn(av[4], av[5])),
                      h2u(__floats2half2_rn(av[6], av[7])));

  float lt[G], mg[G], cb[G], fb[G];
#pragma unroll
  for (int i = 0; i < G; ++i) {
    int b = grp + i * NG;
    float T = rfl(temp[b]);
    lt[i] = rfl(log2f(T * (1.0f / 300.0f)));
    mg[i] = rfl(-1.4426950408889634f / T);
    cb[i] = rfl(crr[b]);
    fb[i] = rfl(fvr[b]);
  }
  unsigned int pc = perm[e16 * NS + t];   // rank-balanced ownership
  __syncthreads();

  // ---- phase 1: rates (f32) -> pack -> f16 multiply by factors ----
#pragma unroll
  for (int it = 0; it < NQ / 512; ++it) {
    int rl = t + 512 * it;
    float4 a4 = pA[rbase + rl];
    float2 bb = pB[rbase + rl];
    int idx = __float_as_int(bb.y);
    uint4 u = abH[idx & 0xffff];
    uint4 v = abH[idx >> 16];
    float r[G];
#pragma unroll
    for (int i = 0; i < G; ++i) {
      float e = __builtin_amdgcn_exp2f(fmaf(a4.y, lt[i], a4.z * mg[i]));
      r[i] = fmaf(a4.x, e, fmaf(a4.w, cb[i], bb.x * fb[i]));
    }
    unsigned int w01 = h2u(__hmul2(bch2(pkrtz(r[0], r[1])),
                                   __hmul2(bch2(u.x), bch2(v.x))));
    unsigned int w23 = h2u(__hmul2(bch2(pkrtz(r[2], r[3])),
                                   __hmul2(bch2(u.y), bch2(v.y))));
    unsigned int w45 = h2u(__hmul2(bch2(pkrtz(r[4], r[5])),
                                   __hmul2(bch2(u.z), bch2(v.z))));
    unsigned int w67 = h2u(__hmul2(bch2(pkrtz(r[6], r[7])),
                                   __hmul2(bch2(u.w), bch2(v.w))));
    gL[rl] = make_uint4(w01, w23, w45, w67);
  }
  __syncthreads();

  // ---- phase 2: gather owned (rank-balanced) species column ----
  int sp = pc & 0xffff;
  int cs = pc >> 16;
  const unsigned short* row = ell + ((size_t)(e16 * NS + sp) << 6);
  __half2 A01 = __float2half2_rn(0.f), A23 = A01, A45 = A01, A67 = A01;
  if (cs > 0) {
    u16x4 ev = *reinterpret_cast<const u16x4*>(row);
    for (int k = 0; k < cs; k += 4) {
      u16x4 cur = ev;
      if (k + 4 < cs) ev = *reinterpret_cast<const u16x4*>(row + k + 4);
      uint4 gg[4];
#pragma unroll
      for (int j = 0; j < 4; ++j) gg[j] = gL[cur[j] & (NQ - 1)];
#pragma unroll
      for (int j = 0; j < 4; ++j) {
        unsigned int m = (k + j) < cs ? 0xFFFFFFFFu : 0u;
        unsigned int se = (cur[j] & 0x8000u) * 0x10001u;  // 0 or 0x80008000
        A01 = __hadd2(A01, bch2((gg[j].x ^ se) & m));
        A23 = __hadd2(A23, bch2((gg[j].y ^ se) & m));
        A45 = __hadd2(A45, bch2((gg[j].z ^ se) & m));
        A67 = __hadd2(A67, bch2((gg[j].w ^ se) & m));
      }
    }
  }

  // ---- de-permute via 8 conflict-free float rows in dead gL, then atomics ----
  float2 o01 = __half22float2(A01);
  float2 o23 = __half22float2(A23);
  float2 o45 = __half22float2(A45);
  float2 o67 = __half22float2(A67);
  __syncthreads();
  float (*stg)[NS] = reinterpret_cast<float(*)[NS]>(gL);
  stg[0][sp] = o01.x; stg[1][sp] = o01.y;
  stg[2][sp] = o23.x; stg[3][sp] = o23.y;
  stg[4][sp] = o45.x; stg[5][sp] = o45.y;
  stg[6][sp] = o67.x; stg[7][sp] = o67.y;
  __syncthreads();
#pragma unroll
  for (int i = 0; i < G; ++i)
    unsafeAtomicAdd(&out[(size_t)(grp + i * NG) * NS + t], stg[i][t]);
}

extern "C" void kernel_launch(void* const* d_in, const int* in_sizes, int n_in,
                              void* d_out, int out_size, void* d_ws, size_t ws_size,
                              hipStream_t stream) {
  const float* ab    = (const float*)d_in[1];
  const float* temp  = (const float*)d_in[2];
  const float* crr   = (const float*)d_in[3];
  const float* fvr   = (const float*)d_in[4];
  const float* inc   = (const float*)d_in[5];
  const float* alpha = (const float*)d_in[6];
  const float* beta  = (const float*)d_in[7];
  const float* gam   = (const float*)d_in[8];
  const float* crc   = (const float*)d_in[9];
  const float* fvc   = (const float*)d_in[10];
  const int*   msi   = (const int*)d_in[12];

  char* ws = (char*)d_ws;
  float4* pA           = (float4*)(ws);
  float2* pB           = (float2*)(ws + 524288);
  int* cnt             = (int*)(ws + 786432);
  unsigned int* perm   = (unsigned int*)(ws + 819200);
  unsigned short* ellp = (unsigned short*)(ws + 851968);
  float* out = (float*)d_out;

  hipMemsetAsync(cnt, 0, Q * NS * sizeof(int), stream);
  build<<<1024, 256, 0, stream>>>(inc, msi, alpha, beta, gam, crc, fvc,
                                  pA, pB, cnt, ellp, out);
  balance<<<Q, 512, 0, stream>>>(cnt, perm);
  fused<<<NG * Q, 512, 0, stream>>>(ab, temp, crr, fvr, pA, pB, perm, ellp, out);
}

// Round 11
// 72.324 us; speedup vs baseline: 1.8131x; 1.1099x over previous
//
#include <hip/hip_runtime.h>
#include <hip/hip_fp16.h>

#define NS 512
#define NR 32768
#define NB 1024
#define Q 16                 // r-splits (sixteenths)
#define NQ (NR / Q)          // 2048 reactions per split
#define G 8                  // batches per block
#define NG (NB / G)          // 128 batch groups
#define ELLK 64              // slots per (split, species); mean 12

typedef unsigned short u16x4 __attribute__((ext_vector_type(4)));

// ws layout (bytes):
//   pA   float4[NR]          @ 0       (524288)  alpha,beta,gamma,cr_coef
//   pB   float2[NR]          @ 524288  (262144)  fuv_coef, (s1|s2<<16) bits
//   cnt  int[Q*NS]           @ 786432  (32768)
//   perm uint[Q*NS]          @ 819200  (32768)   rank -> (s | cnt<<16)
//   ell  u16[Q][NS][ELLK]    @ 851968  (1048576) row-major per species
// total 1,900,544 B

static __device__ __forceinline__ float rfl(float v) {
  return __int_as_float(__builtin_amdgcn_readfirstlane(__float_as_int(v)));
}
static __device__ __forceinline__ unsigned int pkrtz(float a, float b) {
  auto h = __builtin_amdgcn_cvt_pkrtz(a, b);
  return *reinterpret_cast<unsigned int*>(&h);
}
static __device__ __forceinline__ __half2 bch2(unsigned int w) {
  return *reinterpret_cast<__half2*>(&w);
}
static __device__ __forceinline__ unsigned int h2u(__half2 h) {
  return *reinterpret_cast<unsigned int*>(&h);
}

// Merged prep + find_pr + out-zeroing. Grid 1024 = 32 r-blocks x 32 s-blocks.
__global__ __launch_bounds__(256) void build(
    const float* __restrict__ inc, const int* __restrict__ msi,
    const float* __restrict__ alpha, const float* __restrict__ beta,
    const float* __restrict__ gam,   const float* __restrict__ crc,
    const float* __restrict__ fvc,
    float4* __restrict__ pA, float2* __restrict__ pB,
    int* __restrict__ cnt, unsigned short* __restrict__ ell,
    float* __restrict__ out) {
  int rblk = blockIdx.x & 31;
  int sblk = blockIdx.x >> 5;
  int t = threadIdx.x;
  int rbase = rblk * 1024 + 4 * t;

  // ---- pr scan over 16 s-rows ----
  int4 a = reinterpret_cast<const int4*>(msi)[rbase >> 1];
  int4 b = reinterpret_cast<const int4*>(msi)[(rbase >> 1) + 1];
  int s1v[4] = {a.x, a.z, b.x, b.z};
  int s2v[4] = {a.y, a.w, b.y, b.w};
  int pr[4] = {-1, -1, -1, -1};
  int s0 = sblk * 16;
#pragma unroll
  for (int ss = 0; ss < 16; ++ss) {
    int s = s0 + ss;
    float4 v = reinterpret_cast<const float4*>(inc)[((size_t)s * NR + rbase) >> 2];
    float vv[4] = {v.x, v.y, v.z, v.w};
#pragma unroll
    for (int j = 0; j < 4; ++j) {
      float c = vv[j] + (float)(s == s1v[j]) + (float)(s == s2v[j]);
      if (c > 0.5f) pr[j] = s;
    }
  }
#pragma unroll
  for (int j = 0; j < 4; ++j) {
    if (pr[j] >= 0) {
      int r = rbase + j;
      int e16 = r >> 11;
      int p = atomicAdd(&cnt[e16 * NS + pr[j]], 1);
      if (p < ELLK)
        ell[((e16 * NS + pr[j]) << 6) + p] = (unsigned short)(r & (NQ - 1));
    }
  }

  // ---- pack duties: 32 reactions per block ----
  if (t < 32) {
    int r = rblk * 1024 + sblk * 32 + t;
    pA[r] = make_float4(alpha[r], beta[r], gam[r], crc[r]);
    int s1 = msi[2 * r], s2 = msi[2 * r + 1];
    pB[r] = make_float2(fvc[r], __int_as_float(s1 | (s2 << 16)));
    int e16 = r >> 11;
    unsigned short neg = (unsigned short)((r & (NQ - 1)) | 0x8000);
    int p1 = atomicAdd(&cnt[e16 * NS + s1], 1);
    if (p1 < ELLK) ell[((e16 * NS + s1) << 6) + p1] = neg;
    int p2 = atomicAdd(&cnt[e16 * NS + s2], 1);
    if (p2 < ELLK) ell[((e16 * NS + s2) << 6) + p2] = neg;
  }

  // ---- zero d_out slice: 128 float4 per block x 1024 blocks = 2 MB ----
  if (t < 128) {
    reinterpret_cast<float4*>(out)[blockIdx.x * 128 + t] =
        make_float4(0.f, 0.f, 0.f, 0.f);
  }
}

// Per-split descending count-sort of species -> perm[rank] = s | cnt<<16.
__global__ __launch_bounds__(512) void balance(
    const int* __restrict__ cnt, unsigned int* __restrict__ perm) {
  __shared__ unsigned short c[NS];
  int e16 = blockIdx.x;
  int t = threadIdx.x;
  int my = cnt[e16 * NS + t];
  my = my < ELLK ? my : ELLK;
  c[t] = (unsigned short)my;
  __syncthreads();
  int rank = 0;
#pragma unroll 8
  for (int s = 0; s < NS; ++s) {
    int cs = c[s];
    rank += (cs > my) || (cs == my && s < t);
  }
  perm[e16 * NS + rank] = (unsigned int)t | ((unsigned int)my << 16);
}

// One block per (batch-group, split-PAIR). 512 threads, 40 KB LDS -> 4 blocks/CU.
// Grid = NG * Q/2 = 1024 blocks: all resident simultaneously, one round.
__global__ __launch_bounds__(512, 8) void fused(
    const float* __restrict__ ab, const float* __restrict__ temp,
    const float* __restrict__ crr, const float* __restrict__ fvr,
    const float4* __restrict__ pA, const float2* __restrict__ pB,
    const unsigned int* __restrict__ perm, const unsigned short* __restrict__ ell,
    float* __restrict__ out) {
  __shared__ uint4 gL[NQ];            // 32 KB: 4x half2 = 8 batches per reaction
  __shared__ uint4 abH[NS];           // 8 KB: 4x half2 ab per species (8 batches)
  int t = threadIdx.x;
  int grp = blockIdx.x & (NG - 1);
  int ep = blockIdx.x >> 7;           // 0..Q/2-1 -> splits {2ep, 2ep+1}

  float av[G];
#pragma unroll
  for (int i = 0; i < G; ++i) av[i] = ab[(size_t)(grp + i * NG) * NS + t];
  abH[t] = make_uint4(h2u(__floats2half2_rn(av[0], av[1])),
                      h2u(__floats2half2_rn(av[2], av[3])),
                      h2u(__floats2half2_rn(av[4], av[5])),
                      h2u(__floats2half2_rn(av[6], av[7])));

  float lt[G], mg[G], cb[G], fb[G];
#pragma unroll
  for (int i = 0; i < G; ++i) {
    int b = grp + i * NG;
    float T = rfl(temp[b]);
    lt[i] = rfl(log2f(T * (1.0f / 300.0f)));
    mg[i] = rfl(-1.4426950408889634f / T);
    cb[i] = rfl(crr[b]);
    fb[i] = rfl(fvr[b]);
  }

  int spv[2];
  float o[2][G];

#pragma unroll
  for (int half = 0; half < 2; ++half) {
    int e16 = ep * 2 + half;
    int rbase = e16 * NQ;
    unsigned int pc = perm[e16 * NS + t];
    __syncthreads();   // abH ready (half 0) / prior phase-2 gL reads done (half 1)

    // ---- phase 1: rates (f32) -> pack -> f16 multiply by factors ----
#pragma unroll
    for (int it = 0; it < NQ / 512; ++it) {
      int rl = t + 512 * it;
      float4 a4 = pA[rbase + rl];
      float2 bb = pB[rbase + rl];
      int idx = __float_as_int(bb.y);
      uint4 u = abH[idx & 0xffff];
      uint4 v = abH[idx >> 16];
      float r[G];
#pragma unroll
      for (int i = 0; i < G; ++i) {
        float e = __builtin_amdgcn_exp2f(fmaf(a4.y, lt[i], a4.z * mg[i]));
        r[i] = fmaf(a4.x, e, fmaf(a4.w, cb[i], bb.x * fb[i]));
      }
      unsigned int w01 = h2u(__hmul2(bch2(pkrtz(r[0], r[1])),
                                     __hmul2(bch2(u.x), bch2(v.x))));
      unsigned int w23 = h2u(__hmul2(bch2(pkrtz(r[2], r[3])),
                                     __hmul2(bch2(u.y), bch2(v.y))));
      unsigned int w45 = h2u(__hmul2(bch2(pkrtz(r[4], r[5])),
                                     __hmul2(bch2(u.z), bch2(v.z))));
      unsigned int w67 = h2u(__hmul2(bch2(pkrtz(r[6], r[7])),
                                     __hmul2(bch2(u.w), bch2(v.w))));
      gL[rl] = make_uint4(w01, w23, w45, w67);
    }
    __syncthreads();

    // ---- phase 2: gather owned (rank-balanced) species column ----
    int sp = pc & 0xffff;
    int cs = pc >> 16;
    const unsigned short* row = ell + ((size_t)(e16 * NS + sp) << 6);
    __half2 A01 = bch2(0u), A23 = bch2(0u), A45 = bch2(0u), A67 = bch2(0u);
    int csm = cs & ~3;
    for (int k = 0; k < csm; k += 4) {      // main chunks: no tail masking
      u16x4 cur = *reinterpret_cast<const u16x4*>(row + k);
      uint4 gg[4];
#pragma unroll
      for (int j = 0; j < 4; ++j) gg[j] = gL[cur[j] & 0x7fff];
#pragma unroll
      for (int j = 0; j < 4; ++j) {
        __half2 cf = bch2((cur[j] & 0x8000u) ? 0xBC00BC00u : 0x3C003C00u);
        A01 = __hfma2(bch2(gg[j].x), cf, A01);
        A23 = __hfma2(bch2(gg[j].y), cf, A23);
        A45 = __hfma2(bch2(gg[j].z), cf, A45);
        A67 = __hfma2(bch2(gg[j].w), cf, A67);
      }
    }
    if (csm < cs) {                          // single masked tail chunk
      u16x4 cur = *reinterpret_cast<const u16x4*>(row + csm);
#pragma unroll
      for (int j = 0; j < 4; ++j) {
        bool valid = (csm + j) < cs;
        uint4 gg = gL[valid ? (cur[j] & 0x7fff) : 0];
        __half2 cf = bch2(valid ? ((cur[j] & 0x8000u) ? 0xBC00BC00u
                                                      : 0x3C003C00u)
                                : 0u);
        A01 = __hfma2(bch2(gg.x), cf, A01);
        A23 = __hfma2(bch2(gg.y), cf, A23);
        A45 = __hfma2(bch2(gg.z), cf, A45);
        A67 = __hfma2(bch2(gg.w), cf, A67);
      }
    }
    spv[half] = sp;
    float2 f01 = __half22float2(A01), f23 = __half22float2(A23);
    float2 f45 = __half22float2(A45), f67 = __half22float2(A67);
    o[half][0] = f01.x; o[half][1] = f01.y;
    o[half][2] = f23.x; o[half][3] = f23.y;
    o[half][4] = f45.x; o[half][5] = f45.y;
    o[half][6] = f67.x; o[half][7] = f67.y;
  }

  // ---- de-permute both halves via float4 staging overlaid on dead gL ----
  __syncthreads();
  float4* stg = reinterpret_cast<float4*>(gL);   // [NS][2] float4
  stg[spv[0] * 2 + 0] = make_float4(o[0][0], o[0][1], o[0][2], o[0][3]);
  stg[spv[0] * 2 + 1] = make_float4(o[0][4], o[0][5], o[0][6], o[0][7]);
  __syncthreads();
  float4 q0 = stg[spv[1] * 2 + 0];
  float4 q1 = stg[spv[1] * 2 + 1];
  q0.x += o[1][0]; q0.y += o[1][1]; q0.z += o[1][2]; q0.w += o[1][3];
  q1.x += o[1][4]; q1.y += o[1][5]; q1.z += o[1][6]; q1.w += o[1][7];
  stg[spv[1] * 2 + 0] = q0;
  stg[spv[1] * 2 + 1] = q1;
  __syncthreads();
  float4 r0 = stg[t * 2 + 0];
  float4 r1 = stg[t * 2 + 1];
  unsafeAtomicAdd(&out[(size_t)(grp + 0 * NG) * NS + t], r0.x);
  unsafeAtomicAdd(&out[(size_t)(grp + 1 * NG) * NS + t], r0.y);
  unsafeAtomicAdd(&out[(size_t)(grp + 2 * NG) * NS + t], r0.z);
  unsafeAtomicAdd(&out[(size_t)(grp + 3 * NG) * NS + t], r0.w);
  unsafeAtomicAdd(&out[(size_t)(grp + 4 * NG) * NS + t], r1.x);
  unsafeAtomicAdd(&out[(size_t)(grp + 5 * NG) * NS + t], r1.y);
  unsafeAtomicAdd(&out[(size_t)(grp + 6 * NG) * NS + t], r1.z);
  unsafeAtomicAdd(&out[(size_t)(grp + 7 * NG) * NS + t], r1.w);
}

extern "C" void kernel_launch(void* const* d_in, const int* in_sizes, int n_in,
                              void* d_out, int out_size, void* d_ws, size_t ws_size,
                              hipStream_t stream) {
  const float* ab    = (const float*)d_in[1];
  const float* temp  = (const float*)d_in[2];
  const float* crr   = (const float*)d_in[3];
  const float* fvr   = (const float*)d_in[4];
  const float* inc   = (const float*)d_in[5];
  const float* alpha = (const float*)d_in[6];
  const float* beta  = (const float*)d_in[7];
  const float* gam   = (const float*)d_in[8];
  const float* crc   = (const float*)d_in[9];
  const float* fvc   = (const float*)d_in[10];
  const int*   msi   = (const int*)d_in[12];

  char* ws = (char*)d_ws;
  float4* pA           = (float4*)(ws);
  float2* pB           = (float2*)(ws + 524288);
  int* cnt             = (int*)(ws + 786432);
  unsigned int* perm   = (unsigned int*)(ws + 819200);
  unsigned short* ellp = (unsigned short*)(ws + 851968);
  float* out = (float*)d_out;

  hipMemsetAsync(cnt, 0, Q * NS * sizeof(int), stream);
  build<<<1024, 256, 0, stream>>>(inc, msi, alpha, beta, gam, crc, fvc,
                                  pA, pB, cnt, ellp, out);
  balance<<<Q, 512, 0, stream>>>(cnt, perm);
  fused<<<NG * Q / 2, 512, 0, stream>>>(ab, temp, crr, fvr, pA, pB, perm, ellp, out);
}